// Round 1
// baseline (688.598 us; speedup 1.0000x reference)
//
#include <hip/hip_runtime.h>

#define N_SRC 16
#define T_DIM 64
#define GXD 256
#define GYD 256
#define GQD 256
#define HN 4
#define DN 8
#define TILE_I 16
#define OUT_C_ELEMS (2 * T_DIM * GQD * GQD)   // 8388608 floats, then w[16]

__device__ __forceinline__ float unitv(int i) {
    // jnp.linspace(0,1,256): i*(1/255), endpoint forced to 1.0
    return (i == GQD - 1) ? 1.0f : (float)i * (1.0f / 255.0f);
}

__global__ void weights_kernel(const float* __restrict__ params,
                               const float* __restrict__ Wq_w, const float* __restrict__ Wq_b,
                               const float* __restrict__ Wk_w, const float* __restrict__ Wk_b,
                               const float* __restrict__ lyt_p, const float* __restrict__ ccut_p,
                               const float* __restrict__ cnit_p,
                               float* __restrict__ out_w) {
    if (threadIdx.x != 0 || blockIdx.x != 0) return;
    const float lyt = *lyt_p, ccut = *ccut_p, cnit = *cnit_p;
    float tgt[3];
    tgt[0] = (lyt - 30.0f) / 90.0f;
    tgt[1] = ccut / 0.0029f;
    tgt[2] = cnit / 0.0018f;
    float q[HN * DN];
    for (int hd = 0; hd < HN * DN; ++hd)
        q[hd] = tgt[0] * Wq_w[hd * 3 + 0] + tgt[1] * Wq_w[hd * 3 + 1] + tgt[2] * Wq_w[hd * 3 + 2] + Wq_b[hd];
    float p[N_SRC][3];
    float attn[N_SRC][HN];
    for (int n = 0; n < N_SRC; ++n) {
        p[n][0] = (params[n * 3 + 0] - 30.0f) / 90.0f;
        p[n][1] = params[n * 3 + 1] / 0.0029f;
        p[n][2] = params[n * 3 + 2] / 0.0018f;
        for (int h = 0; h < HN; ++h) {
            float acc = 0.0f;
            for (int d = 0; d < DN; ++d) {
                int hd = h * DN + d;
                float kv = p[n][0] * Wk_w[hd * 3 + 0] + p[n][1] * Wk_w[hd * 3 + 1] + p[n][2] * Wk_w[hd * 3 + 2] + Wk_b[hd];
                acc += kv * q[hd];
            }
            attn[n][h] = acc / sqrtf(8.0f);
        }
    }
    // softmax over n (per head) with max-subtraction, then mean over heads
    float aw[N_SRC];
    for (int n = 0; n < N_SRC; ++n) aw[n] = 0.0f;
    for (int h = 0; h < HN; ++h) {
        float m = attn[0][h];
        for (int n = 1; n < N_SRC; ++n) m = fmaxf(m, attn[n][h]);
        float e[N_SRC], s = 0.0f;
        for (int n = 0; n < N_SRC; ++n) { e[n] = expf(attn[n][h] - m); s += e[n]; }
        for (int n = 0; n < N_SRC; ++n) aw[n] += e[n] / s;
    }
    for (int n = 0; n < N_SRC; ++n) aw[n] *= (1.0f / (float)HN);
    // gaussian similarity weights, normalized
    float sw[N_SRC], ss = 0.0f;
    for (int n = 0; n < N_SRC; ++n) {
        float d0 = (p[n][0] - tgt[0]) / 0.2f;
        float d1 = (p[n][1] - tgt[1]) / 0.2f;
        float d2 = (p[n][2] - tgt[2]) / 0.2f;
        sw[n] = expf(-0.5f * (d0 * d0 + d1 * d1 + d2 * d2));
        ss += sw[n];
    }
    float w[N_SRC], wsum = 0.0f;
    for (int n = 0; n < N_SRC; ++n) { w[n] = aw[n] * (sw[n] / ss); wsum += w[n]; }
    for (int n = 0; n < N_SRC; ++n) out_w[n] = w[n] / wsum;
}

__global__ __launch_bounds__(256) void fused_kernel(
    const float* __restrict__ c1, const float* __restrict__ c2,
    const float* __restrict__ xg, const float* __restrict__ yg,
    const float* __restrict__ params,
    const float* __restrict__ lyt_p, const float* __restrict__ ccut_p,
    const float* __restrict__ cnit_p,
    const float* __restrict__ wbuf, float* __restrict__ out)
{
    __shared__ float xg_sm[GXD];
    __shared__ float ys_sm[N_SRC][GYD];
    __shared__ float w_sm[N_SRC];

    const int tid = threadIdx.x;
    const int t = blockIdx.y;
    const int i0 = blockIdx.x * TILE_I;
    const float lyt = *lyt_p;

    xg_sm[tid] = xg[tid];  // x_grids row 0 (all rows identical)
    #pragma unroll
    for (int n = 0; n < N_SRC; ++n) {
        // prescale into LDS: matches reference's materialized f32 array
        // ys[n][m] = fl( y_grids[n][m] * fl(ly_target / lys[n]) )
        float s = lyt / params[n * 3 + 0];
        ys_sm[n][tid] = yg[n * GYD + tid] * s;
    }
    if (tid < N_SRC) w_sm[tid] = wbuf[tid];
    __syncthreads();

    const int j = tid;
    const float qy = unitv(j) * lyt;
    int iy[N_SRC];
    float wy0[N_SRC], wy1[N_SRC];
    #pragma unroll
    for (int n = 0; n < N_SRC; ++n) {
        // searchsorted(ys, qy, 'right') - 1, clipped to [0, GY-2]
        int lo = 0, hi = GYD;
        while (lo < hi) { int mid = (lo + hi) >> 1; if (ys_sm[n][mid] <= qy) lo = mid + 1; else hi = mid; }
        int idx = lo - 1;
        idx = idx < 0 ? 0 : (idx > GYD - 2 ? GYD - 2 : idx);
        iy[n] = idx;
        float y0 = ys_sm[n][idx], y1 = ys_sm[n][idx + 1];
        float fy = (qy - y0) / (y1 - y0);
        float vy = (qy >= ys_sm[n][0] && qy <= ys_sm[n][GYD - 1]) ? 1.0f : 0.0f;
        float wn = w_sm[n] * vy;
        wy0[n] = wn * (1.0f - fy);
        wy1[n] = wn * fy;
    }

    const float Lx = xg_sm[GXD - 1];
    const float ccut = *ccut_p, cnit = *cnit_p;

    for (int ii = 0; ii < TILE_I; ++ii) {
        const int i = i0 + ii;
        const float qx = unitv(i) * Lx;
        int lo = 0, hi = GXD;
        while (lo < hi) { int mid = (lo + hi) >> 1; if (xg_sm[mid] <= qx) lo = mid + 1; else hi = mid; }
        int ixi = lo - 1;
        ixi = ixi < 0 ? 0 : (ixi > GXD - 2 ? GXD - 2 : ixi);
        const float x0 = xg_sm[ixi], x1 = xg_sm[ixi + 1];
        const float fx = (qx - x0) / (x1 - x0);
        const float vx = (qx >= xg_sm[0] && qx <= xg_sm[GXD - 1]) ? 1.0f : 0.0f;

        float a10 = 0.0f, a11 = 0.0f, a20 = 0.0f, a21 = 0.0f;
        #pragma unroll
        for (int n = 0; n < N_SRC; ++n) {
            const int base = ((n * T_DIM + t) * GXD + ixi) * GYD + iy[n];
            const float e00 = c1[base],       e01 = c1[base + 1];
            const float e10 = c1[base + GYD], e11 = c1[base + GYD + 1];
            a10 += wy0[n] * e00 + wy1[n] * e01;
            a11 += wy0[n] * e10 + wy1[n] * e11;
            const float f00 = c2[base],       f01 = c2[base + 1];
            const float f10 = c2[base + GYD], f11 = c2[base + GYD + 1];
            a20 += wy0[n] * f00 + wy1[n] * f01;
            a21 += wy0[n] * f10 + wy1[n] * f11;
        }
        float o1 = vx * ((1.0f - fx) * a10 + fx * a11);
        float o2 = vx * ((1.0f - fx) * a20 + fx * a21);
        if (j == 0) o1 = ccut;          // c1[:, :, 0]  = c_cu_target
        if (j == GQD - 1) o2 = cnit;    // c2[:, :, -1] = c_ni_target
        out[(t * GQD + i) * GQD + j] = o1;
        out[((T_DIM + t) * GQD + i) * GQD + j] = o2;
    }
}

extern "C" void kernel_launch(void* const* d_in, const int* in_sizes, int n_in,
                              void* d_out, int out_size, void* d_ws, size_t ws_size,
                              hipStream_t stream) {
    const float* c1     = (const float*)d_in[0];
    const float* c2     = (const float*)d_in[1];
    const float* xg     = (const float*)d_in[2];
    const float* yg     = (const float*)d_in[3];
    const float* params = (const float*)d_in[4];
    const float* Wq_w   = (const float*)d_in[5];
    const float* Wq_b   = (const float*)d_in[6];
    const float* Wk_w   = (const float*)d_in[7];
    const float* Wk_b   = (const float*)d_in[8];
    const float* lyt    = (const float*)d_in[9];
    const float* ccut   = (const float*)d_in[10];
    const float* cnit   = (const float*)d_in[11];
    float* out = (float*)d_out;
    float* out_w = out + OUT_C_ELEMS;  // w[16] tail of the tuple output

    weights_kernel<<<1, 64, 0, stream>>>(params, Wq_w, Wq_b, Wk_w, Wk_b, lyt, ccut, cnit, out_w);
    dim3 grid(GQD / TILE_I, T_DIM);
    fused_kernel<<<grid, 256, 0, stream>>>(c1, c2, xg, yg, params, lyt, ccut, cnit, out_w, out);
}

// Round 2
// 685.770 us; speedup vs baseline: 1.0041x; 1.0041x over previous
//
#include <hip/hip_runtime.h>

#define N_SRC 16
#define T_DIM 64
#define GXD 256
#define GYD 256
#define GQD 256
#define HN 4
#define DN 8
#define OUT_C_ELEMS (2 * T_DIM * GQD * GQD)   // 8388608 floats, then w[16]

// d_ws layout (bytes):
//   iy_tab  : int  [N_SRC*GQD]  @ 0
//   wy0_tab : float[N_SRC*GQD]  @ 16384
//   wy1_tab : float[N_SRC*GQD]  @ 32768
//   ix_tab  : int  [GQD]        @ 49152
//   wx0_tab : float[GQD]        @ 50176
//   wx1_tab : float[GQD]        @ 51200
#define WS_IY   0
#define WS_WY0  16384
#define WS_WY1  32768
#define WS_IX   49152
#define WS_WX0  50176
#define WS_WX1  51200

__device__ __forceinline__ float unitv(int i) {
    // jnp.linspace(0,1,256): i*(1/255), endpoint forced to 1.0
    return (i == GQD - 1) ? 1.0f : (float)i * (1.0f / 255.0f);
}

// One block, 256 threads. Computes attention/gaussian weights w[16] (thread 0),
// writes w to out tail, and builds the per-j y-tables and per-i x-tables in ws.
__global__ __launch_bounds__(256) void table_kernel(
    const float* __restrict__ xg, const float* __restrict__ yg,
    const float* __restrict__ params,
    const float* __restrict__ Wq_w, const float* __restrict__ Wq_b,
    const float* __restrict__ Wk_w, const float* __restrict__ Wk_b,
    const float* __restrict__ lyt_p, const float* __restrict__ ccut_p,
    const float* __restrict__ cnit_p,
    float* __restrict__ out_w, char* __restrict__ ws)
{
    __shared__ float xg_sm[GXD];
    __shared__ float ys_sm[N_SRC][GYD];
    __shared__ float w_sm[N_SRC];

    const int tid = threadIdx.x;
    const float lyt = *lyt_p;

    xg_sm[tid] = xg[tid];  // x_grids row 0 (all rows identical)
    #pragma unroll
    for (int n = 0; n < N_SRC; ++n) {
        // prescale: matches reference's materialized f32 ys array exactly
        float s = lyt / params[n * 3 + 0];
        ys_sm[n][tid] = yg[n * GYD + tid] * s;
    }

    if (tid == 0) {
        const float ccut = *ccut_p, cnit = *cnit_p;
        float tgt[3];
        tgt[0] = (lyt - 30.0f) / 90.0f;
        tgt[1] = ccut / 0.0029f;
        tgt[2] = cnit / 0.0018f;
        float q[HN * DN];
        for (int hd = 0; hd < HN * DN; ++hd)
            q[hd] = tgt[0] * Wq_w[hd * 3 + 0] + tgt[1] * Wq_w[hd * 3 + 1] + tgt[2] * Wq_w[hd * 3 + 2] + Wq_b[hd];
        float p[N_SRC][3];
        float attn[N_SRC][HN];
        for (int n = 0; n < N_SRC; ++n) {
            p[n][0] = (params[n * 3 + 0] - 30.0f) / 90.0f;
            p[n][1] = params[n * 3 + 1] / 0.0029f;
            p[n][2] = params[n * 3 + 2] / 0.0018f;
            for (int h = 0; h < HN; ++h) {
                float acc = 0.0f;
                for (int d = 0; d < DN; ++d) {
                    int hd = h * DN + d;
                    float kv = p[n][0] * Wk_w[hd * 3 + 0] + p[n][1] * Wk_w[hd * 3 + 1] + p[n][2] * Wk_w[hd * 3 + 2] + Wk_b[hd];
                    acc += kv * q[hd];
                }
                attn[n][h] = acc / sqrtf(8.0f);
            }
        }
        float aw[N_SRC];
        for (int n = 0; n < N_SRC; ++n) aw[n] = 0.0f;
        for (int h = 0; h < HN; ++h) {
            float m = attn[0][h];
            for (int n = 1; n < N_SRC; ++n) m = fmaxf(m, attn[n][h]);
            float e[N_SRC], s = 0.0f;
            for (int n = 0; n < N_SRC; ++n) { e[n] = expf(attn[n][h] - m); s += e[n]; }
            for (int n = 0; n < N_SRC; ++n) aw[n] += e[n] / s;
        }
        for (int n = 0; n < N_SRC; ++n) aw[n] *= (1.0f / (float)HN);
        float sw[N_SRC], ss = 0.0f;
        for (int n = 0; n < N_SRC; ++n) {
            float d0 = (p[n][0] - tgt[0]) / 0.2f;
            float d1 = (p[n][1] - tgt[1]) / 0.2f;
            float d2 = (p[n][2] - tgt[2]) / 0.2f;
            sw[n] = expf(-0.5f * (d0 * d0 + d1 * d1 + d2 * d2));
            ss += sw[n];
        }
        float w[N_SRC], wsum = 0.0f;
        for (int n = 0; n < N_SRC; ++n) { w[n] = aw[n] * (sw[n] / ss); wsum += w[n]; }
        for (int n = 0; n < N_SRC; ++n) {
            float wf = w[n] / wsum;
            w_sm[n] = wf;
            out_w[n] = wf;
        }
    }
    __syncthreads();

    int*   iy_tab  = (int*)  (ws + WS_IY);
    float* wy0_tab = (float*)(ws + WS_WY0);
    float* wy1_tab = (float*)(ws + WS_WY1);
    int*   ix_tab  = (int*)  (ws + WS_IX);
    float* wx0_tab = (float*)(ws + WS_WX0);
    float* wx1_tab = (float*)(ws + WS_WX1);

    const int j = tid;
    const float qy = unitv(j) * lyt;
    #pragma unroll
    for (int n = 0; n < N_SRC; ++n) {
        // searchsorted(ys, qy, 'right') - 1, clipped to [0, GY-2]
        int lo = 0, hi = GYD;
        while (lo < hi) { int mid = (lo + hi) >> 1; if (ys_sm[n][mid] <= qy) lo = mid + 1; else hi = mid; }
        int idx = lo - 1;
        idx = idx < 0 ? 0 : (idx > GYD - 2 ? GYD - 2 : idx);
        float y0 = ys_sm[n][idx], y1 = ys_sm[n][idx + 1];
        float fy = (qy - y0) / (y1 - y0);
        float vy = (qy >= ys_sm[n][0] && qy <= ys_sm[n][GYD - 1]) ? 1.0f : 0.0f;
        float wn = w_sm[n] * vy;
        iy_tab [n * GQD + j] = idx;
        wy0_tab[n * GQD + j] = wn * (1.0f - fy);
        wy1_tab[n * GQD + j] = wn * fy;
    }

    // x-tables: i = tid
    const float Lx = xg_sm[GXD - 1];
    const float qx = unitv(tid) * Lx;
    int lo = 0, hi = GXD;
    while (lo < hi) { int mid = (lo + hi) >> 1; if (xg_sm[mid] <= qx) lo = mid + 1; else hi = mid; }
    int ixi = lo - 1;
    ixi = ixi < 0 ? 0 : (ixi > GXD - 2 ? GXD - 2 : ixi);
    const float x0 = xg_sm[ixi], x1 = xg_sm[ixi + 1];
    const float fx = (qx - x0) / (x1 - x0);
    const float vx = (qx >= xg_sm[0] && qx <= xg_sm[GXD - 1]) ? 1.0f : 0.0f;
    ix_tab [tid] = ixi;
    wx0_tab[tid] = vx * (1.0f - fx);
    wx1_tab[tid] = vx * fx;
}

// Grid: (i=256, t=64). Block: 256 threads = j. Pure gather + FMA, no LDS.
__global__ __launch_bounds__(256) void fused_kernel(
    const float* __restrict__ c1, const float* __restrict__ c2,
    const float* __restrict__ ccut_p, const float* __restrict__ cnit_p,
    const char* __restrict__ ws, float* __restrict__ out)
{
    const int i = blockIdx.x;
    const int t = blockIdx.y;
    const int j = threadIdx.x;

    const int*   iy_tab  = (const int*)  (ws + WS_IY);
    const float* wy0_tab = (const float*)(ws + WS_WY0);
    const float* wy1_tab = (const float*)(ws + WS_WY1);

    // wave-uniform x parameters (scalar loads)
    const int   ixi = ((const int*)  (ws + WS_IX)) [i];
    const float wx0 = ((const float*)(ws + WS_WX0))[i];
    const float wx1 = ((const float*)(ws + WS_WX1))[i];

    float a10 = 0.0f, a11 = 0.0f, a20 = 0.0f, a21 = 0.0f;

    #pragma unroll 4
    for (int n = 0; n < N_SRC; ++n) {
        const int   iy  = iy_tab [n * GQD + j];
        const float wy0 = wy0_tab[n * GQD + j];
        const float wy1 = wy1_tab[n * GQD + j];
        const int base = ((n * T_DIM + t) * GXD + ixi) * GYD + iy;
        const float e00 = c1[base],       e01 = c1[base + 1];
        const float e10 = c1[base + GYD], e11 = c1[base + GYD + 1];
        a10 += wy0 * e00 + wy1 * e01;
        a11 += wy0 * e10 + wy1 * e11;
        const float f00 = c2[base],       f01 = c2[base + 1];
        const float f10 = c2[base + GYD], f11 = c2[base + GYD + 1];
        a20 += wy0 * f00 + wy1 * f01;
        a21 += wy0 * f10 + wy1 * f11;
    }

    float o1 = wx0 * a10 + wx1 * a11;
    float o2 = wx0 * a20 + wx1 * a21;
    if (j == 0)       o1 = *ccut_p;   // c1[:, :, 0]  = c_cu_target
    if (j == GQD - 1) o2 = *cnit_p;   // c2[:, :, -1] = c_ni_target
    out[(t * GQD + i) * GQD + j] = o1;
    out[((T_DIM + t) * GQD + i) * GQD + j] = o2;
}

extern "C" void kernel_launch(void* const* d_in, const int* in_sizes, int n_in,
                              void* d_out, int out_size, void* d_ws, size_t ws_size,
                              hipStream_t stream) {
    const float* c1     = (const float*)d_in[0];
    const float* c2     = (const float*)d_in[1];
    const float* xg     = (const float*)d_in[2];
    const float* yg     = (const float*)d_in[3];
    const float* params = (const float*)d_in[4];
    const float* Wq_w   = (const float*)d_in[5];
    const float* Wq_b   = (const float*)d_in[6];
    const float* Wk_w   = (const float*)d_in[7];
    const float* Wk_b   = (const float*)d_in[8];
    const float* lyt    = (const float*)d_in[9];
    const float* ccut   = (const float*)d_in[10];
    const float* cnit   = (const float*)d_in[11];
    float* out = (float*)d_out;
    float* out_w = out + OUT_C_ELEMS;  // w[16] tail of the tuple output
    char* ws = (char*)d_ws;

    table_kernel<<<1, 256, 0, stream>>>(xg, yg, params, Wq_w, Wq_b, Wk_w, Wk_b,
                                        lyt, ccut, cnit, out_w, ws);
    dim3 grid(GQD, T_DIM);  // i fastest-varying: adjacent blocks share an x-row (L2/L3 reuse)
    fused_kernel<<<grid, 256, 0, stream>>>(c1, c2, ccut, cnit, ws, out);
}

// Round 3
// 630.825 us; speedup vs baseline: 1.0916x; 1.0871x over previous
//
#include <hip/hip_runtime.h>

#define N_SRC 16
#define T_DIM 64
#define GXD 256
#define GYD 256
#define GQD 256
#define HN 4
#define DN 8
#define TI 16              // i-tile per block
#define MAXROWS 18         // staged x-rows per plane (monotone ixi => <= 18)
#define OUT_C_ELEMS (2 * T_DIM * GQD * GQD)   // 8388608 floats, then w[16]

// d_ws layout (bytes):
#define WS_IY   0          // int  [N_SRC*GQD]
#define WS_WY0  16384      // float[N_SRC*GQD]
#define WS_WY1  32768      // float[N_SRC*GQD]
#define WS_IX   49152      // int  [GQD]
#define WS_WX0  50176      // float[GQD]
#define WS_WX1  51200      // float[GQD]

__device__ __forceinline__ float unitv(int i) {
    // jnp.linspace(0,1,256): i*(1/255), endpoint forced to 1.0
    return (i == GQD - 1) ? 1.0f : (float)i * (1.0f / 255.0f);
}

// One block, 256 threads: attention/gaussian weights w[16] + y/x interp tables.
__global__ __launch_bounds__(256) void table_kernel(
    const float* __restrict__ xg, const float* __restrict__ yg,
    const float* __restrict__ params,
    const float* __restrict__ Wq_w, const float* __restrict__ Wq_b,
    const float* __restrict__ Wk_w, const float* __restrict__ Wk_b,
    const float* __restrict__ lyt_p, const float* __restrict__ ccut_p,
    const float* __restrict__ cnit_p,
    float* __restrict__ out_w, char* __restrict__ ws)
{
    __shared__ float xg_sm[GXD];
    __shared__ float ys_sm[N_SRC][GYD];
    __shared__ float w_sm[N_SRC];

    const int tid = threadIdx.x;
    const float lyt = *lyt_p;

    xg_sm[tid] = xg[tid];  // x_grids row 0 (all rows identical)
    #pragma unroll
    for (int n = 0; n < N_SRC; ++n) {
        // prescale: matches reference's materialized f32 ys array exactly
        float s = lyt / params[n * 3 + 0];
        ys_sm[n][tid] = yg[n * GYD + tid] * s;
    }

    if (tid == 0) {
        const float ccut = *ccut_p, cnit = *cnit_p;
        float tgt[3];
        tgt[0] = (lyt - 30.0f) / 90.0f;
        tgt[1] = ccut / 0.0029f;
        tgt[2] = cnit / 0.0018f;
        float q[HN * DN];
        for (int hd = 0; hd < HN * DN; ++hd)
            q[hd] = tgt[0] * Wq_w[hd * 3 + 0] + tgt[1] * Wq_w[hd * 3 + 1] + tgt[2] * Wq_w[hd * 3 + 2] + Wq_b[hd];
        float p[N_SRC][3];
        float attn[N_SRC][HN];
        for (int n = 0; n < N_SRC; ++n) {
            p[n][0] = (params[n * 3 + 0] - 30.0f) / 90.0f;
            p[n][1] = params[n * 3 + 1] / 0.0029f;
            p[n][2] = params[n * 3 + 2] / 0.0018f;
            for (int h = 0; h < HN; ++h) {
                float acc = 0.0f;
                for (int d = 0; d < DN; ++d) {
                    int hd = h * DN + d;
                    float kv = p[n][0] * Wk_w[hd * 3 + 0] + p[n][1] * Wk_w[hd * 3 + 1] + p[n][2] * Wk_w[hd * 3 + 2] + Wk_b[hd];
                    acc += kv * q[hd];
                }
                attn[n][h] = acc / sqrtf(8.0f);
            }
        }
        float aw[N_SRC];
        for (int n = 0; n < N_SRC; ++n) aw[n] = 0.0f;
        for (int h = 0; h < HN; ++h) {
            float m = attn[0][h];
            for (int n = 1; n < N_SRC; ++n) m = fmaxf(m, attn[n][h]);
            float e[N_SRC], s = 0.0f;
            for (int n = 0; n < N_SRC; ++n) { e[n] = expf(attn[n][h] - m); s += e[n]; }
            for (int n = 0; n < N_SRC; ++n) aw[n] += e[n] / s;
        }
        for (int n = 0; n < N_SRC; ++n) aw[n] *= (1.0f / (float)HN);
        float sw[N_SRC], ss = 0.0f;
        for (int n = 0; n < N_SRC; ++n) {
            float d0 = (p[n][0] - tgt[0]) / 0.2f;
            float d1 = (p[n][1] - tgt[1]) / 0.2f;
            float d2 = (p[n][2] - tgt[2]) / 0.2f;
            sw[n] = expf(-0.5f * (d0 * d0 + d1 * d1 + d2 * d2));
            ss += sw[n];
        }
        float w[N_SRC], wsum = 0.0f;
        for (int n = 0; n < N_SRC; ++n) { w[n] = aw[n] * (sw[n] / ss); wsum += w[n]; }
        for (int n = 0; n < N_SRC; ++n) {
            float wf = w[n] / wsum;
            w_sm[n] = wf;
            out_w[n] = wf;
        }
    }
    __syncthreads();

    int*   iy_tab  = (int*)  (ws + WS_IY);
    float* wy0_tab = (float*)(ws + WS_WY0);
    float* wy1_tab = (float*)(ws + WS_WY1);
    int*   ix_tab  = (int*)  (ws + WS_IX);
    float* wx0_tab = (float*)(ws + WS_WX0);
    float* wx1_tab = (float*)(ws + WS_WX1);

    const int j = tid;
    const float qy = unitv(j) * lyt;
    #pragma unroll
    for (int n = 0; n < N_SRC; ++n) {
        int lo = 0, hi = GYD;
        while (lo < hi) { int mid = (lo + hi) >> 1; if (ys_sm[n][mid] <= qy) lo = mid + 1; else hi = mid; }
        int idx = lo - 1;
        idx = idx < 0 ? 0 : (idx > GYD - 2 ? GYD - 2 : idx);
        float y0 = ys_sm[n][idx], y1 = ys_sm[n][idx + 1];
        float fy = (qy - y0) / (y1 - y0);
        float vy = (qy >= ys_sm[n][0] && qy <= ys_sm[n][GYD - 1]) ? 1.0f : 0.0f;
        float wn = w_sm[n] * vy;
        iy_tab [n * GQD + j] = idx;
        wy0_tab[n * GQD + j] = wn * (1.0f - fy);
        wy1_tab[n * GQD + j] = wn * fy;
    }

    const float Lx = xg_sm[GXD - 1];
    const float qx = unitv(tid) * Lx;
    int lo = 0, hi = GXD;
    while (lo < hi) { int mid = (lo + hi) >> 1; if (xg_sm[mid] <= qx) lo = mid + 1; else hi = mid; }
    int ixi = lo - 1;
    ixi = ixi < 0 ? 0 : (ixi > GXD - 2 ? GXD - 2 : ixi);
    const float x0 = xg_sm[ixi], x1 = xg_sm[ixi + 1];
    const float fx = (qx - x0) / (x1 - x0);
    const float vx = (qx >= xg_sm[0] && qx <= xg_sm[GXD - 1]) ? 1.0f : 0.0f;
    ix_tab [tid] = ixi;
    wx0_tab[tid] = vx * (1.0f - fx);
    wx1_tab[tid] = vx * fx;
}

__device__ __forceinline__ void gl_lds16(const float4* g, float4* l) {
    __builtin_amdgcn_global_load_lds(
        (const __attribute__((address_space(1))) void*)g,
        (__attribute__((address_space(3))) void*)l, 16, 0, 0);
}

// Grid: (GQD/TI, T_DIM). Block 256 = j. LDS-staged, coalesced, double-buffered.
__global__ __launch_bounds__(256) void fused_kernel(
    const float* __restrict__ c1, const float* __restrict__ c2,
    const float* __restrict__ ccut_p, const float* __restrict__ cnit_p,
    const char* __restrict__ ws, float* __restrict__ out)
{
    __shared__ float buf[2][MAXROWS * GYD];   // 2 x 18 KB
    __shared__ int   ixb_sm[TI];
    __shared__ float wx0_sm[TI], wx1_sm[TI];

    const int tid = threadIdx.x;
    const int j = tid;
    const int i0 = blockIdx.x * TI;
    const int t = blockIdx.y;

    const int*   iy_tab  = (const int*)  (ws + WS_IY);
    const float* wy0_tab = (const float*)(ws + WS_WY0);
    const float* wy1_tab = (const float*)(ws + WS_WY1);

    if (tid < TI) {
        ixb_sm[tid] = ((const int*)  (ws + WS_IX)) [i0 + tid];
        wx0_sm[tid] = ((const float*)(ws + WS_WX0))[i0 + tid];
        wx1_sm[tid] = ((const float*)(ws + WS_WX1))[i0 + tid];
    }
    __syncthreads();

    const int x0r = ixb_sm[0];
    int nrows = ixb_sm[TI - 1] + 2 - x0r;
    nrows = nrows > MAXROWS ? MAXROWS : nrows;      // safety clamp (can't trigger: ixi monotone, ixi[i] in {i-1,i})
    const int chunks4 = nrows * (GYD / 4);          // float4 chunks per plane, <= 1152

    int   r0r[TI];
    float wx0r[TI], wx1r[TI];
    #pragma unroll
    for (int ii = 0; ii < TI; ++ii) {
        r0r[ii]  = ixb_sm[ii] - x0r;
        wx0r[ii] = wx0_sm[ii];
        wx1r[ii] = wx1_sm[ii];
    }

    float acc1[TI], acc2[TI];
    #pragma unroll
    for (int ii = 0; ii < TI; ++ii) { acc1[ii] = 0.0f; acc2[ii] = 0.0f; }

    // plane p = n*2 + ch; source base for plane: ((n*T+t)*GX + x0r)*GY
    auto plane_src = [&](int p) -> const float4* {
        const int n = p >> 1;
        const float* base = (p & 1) ? c2 : c1;
        return (const float4*)(base + (((size_t)n * T_DIM + t) * GXD + x0r) * GYD);
    };

    // issue plane 0 into buf[0]
    {
        const float4* g = plane_src(0);
        float4* l = (float4*)&buf[0][0];
        #pragma unroll
        for (int k = 0; k < 5; ++k) {
            int c = tid + k * 256;
            if (c < chunks4) gl_lds16(g + c, l + c);
        }
    }

    int   iyv = 0;
    float wy0v = 0.0f, wy1v = 0.0f;

    for (int p = 0; p < 2 * N_SRC; ++p) {
        // plane p's loads complete; also all waves done consuming buf[p&1]'s previous tenant
        __builtin_amdgcn_s_waitcnt(0);   // vmcnt(0) lgkmcnt(0) — conservative
        __syncthreads();

        if (p + 1 < 2 * N_SRC) {
            const float4* g = plane_src(p + 1);
            float4* l = (float4*)&buf[(p + 1) & 1][0];
            #pragma unroll
            for (int k = 0; k < 5; ++k) {
                int c = tid + k * 256;
                if (c < chunks4) gl_lds16(g + c, l + c);
            }
        }

        const int n = p >> 1;
        if ((p & 1) == 0) {              // tables shared by both channels of n
            iyv  = iy_tab [n * GQD + j];
            wy0v = wy0_tab[n * GQD + j];
            wy1v = wy1_tab[n * GQD + j];
        }

        // consume plane p: rolling per-row y-interp, rows shared across adjacent i
        const float* B = &buf[p & 1][0];
        int loaded = -1;
        float vm1 = 0.0f, vcur = 0.0f;
        if ((p & 1) == 0) {
            #pragma unroll
            for (int ii = 0; ii < TI; ++ii) {
                const int r1 = r0r[ii] + 1;
                while (loaded < r1) {
                    ++loaded;
                    vm1 = vcur;
                    vcur = wy0v * B[loaded * GYD + iyv] + wy1v * B[loaded * GYD + iyv + 1];
                }
                acc1[ii] += wx0r[ii] * vm1 + wx1r[ii] * vcur;
            }
        } else {
            #pragma unroll
            for (int ii = 0; ii < TI; ++ii) {
                const int r1 = r0r[ii] + 1;
                while (loaded < r1) {
                    ++loaded;
                    vm1 = vcur;
                    vcur = wy0v * B[loaded * GYD + iyv] + wy1v * B[loaded * GYD + iyv + 1];
                }
                acc2[ii] += wx0r[ii] * vm1 + wx1r[ii] * vcur;
            }
        }
    }

    const float ccut = *ccut_p, cnit = *cnit_p;
    #pragma unroll
    for (int ii = 0; ii < TI; ++ii) {
        const int i = i0 + ii;
        float o1 = acc1[ii];
        float o2 = acc2[ii];
        if (j == 0)       o1 = ccut;   // c1[:, :, 0]  = c_cu_target
        if (j == GQD - 1) o2 = cnit;   // c2[:, :, -1] = c_ni_target
        out[(t * GQD + i) * GQD + j] = o1;
        out[((T_DIM + t) * GQD + i) * GQD + j] = o2;
    }
}

extern "C" void kernel_launch(void* const* d_in, const int* in_sizes, int n_in,
                              void* d_out, int out_size, void* d_ws, size_t ws_size,
                              hipStream_t stream) {
    const float* c1     = (const float*)d_in[0];
    const float* c2     = (const float*)d_in[1];
    const float* xg     = (const float*)d_in[2];
    const float* yg     = (const float*)d_in[3];
    const float* params = (const float*)d_in[4];
    const float* Wq_w   = (const float*)d_in[5];
    const float* Wq_b   = (const float*)d_in[6];
    const float* Wk_w   = (const float*)d_in[7];
    const float* Wk_b   = (const float*)d_in[8];
    const float* lyt    = (const float*)d_in[9];
    const float* ccut   = (const float*)d_in[10];
    const float* cnit   = (const float*)d_in[11];
    float* out = (float*)d_out;
    float* out_w = out + OUT_C_ELEMS;  // w[16] tail of the tuple output
    char* ws = (char*)d_ws;

    table_kernel<<<1, 256, 0, stream>>>(xg, yg, params, Wq_w, Wq_b, Wk_w, Wk_b,
                                        lyt, ccut, cnit, out_w, ws);
    dim3 grid(GQD / TI, T_DIM);
    fused_kernel<<<grid, 256, 0, stream>>>(c1, c2, ccut, cnit, ws, out);
}